// Round 1
// baseline (503.124 us; speedup 1.0000x reference)
//
#include <hip/hip_runtime.h>
#include <math.h>

#define WAVE 64

// ---------------- histogram of dst degrees ----------------
__global__ __launch_bounds__(256) void k_hist(const int* __restrict__ dst,
                                              int* __restrict__ deg, int E_) {
    int e = blockIdx.x * 256 + threadIdx.x;
    if (e < E_) atomicAdd(&deg[dst[e]], 1);
}

// ---------------- single-block exclusive scan (wave-based) ----------------
__global__ __launch_bounds__(1024) void k_scan(const int* __restrict__ deg,
                                               int* __restrict__ rowptr,
                                               int* __restrict__ cursor, int n) {
    __shared__ int wsum[16];
    __shared__ int s_carry;
    int tid = threadIdx.x, lane = tid & 63, w = tid >> 6;
    if (tid == 0) { s_carry = 0; rowptr[0] = 0; }
    __syncthreads();
    for (int base = 0; base < n; base += 1024) {
        int i = base + tid;
        int v = (i < n) ? deg[i] : 0;
        int incl = v;
        #pragma unroll
        for (int o = 1; o < 64; o <<= 1) {
            int t = __shfl_up(incl, o);
            if (lane >= o) incl += t;
        }
        if (lane == 63) wsum[w] = incl;
        __syncthreads();
        if (w == 0) {
            int s = (lane < 16) ? wsum[lane] : 0;
            #pragma unroll
            for (int o = 1; o < 16; o <<= 1) {
                int t = __shfl_up(s, o);
                if (lane >= o) s += t;
            }
            if (lane < 16) wsum[lane] = s;
        }
        __syncthreads();
        int carry = s_carry;
        int waveoff = (w == 0) ? 0 : wsum[w - 1];
        int excl = carry + waveoff + incl - v;
        if (i < n) { cursor[i] = excl; rowptr[i + 1] = excl + v; }
        __syncthreads();                 // everyone read s_carry
        if (tid == 1023) s_carry = carry + wsum[15];
        __syncthreads();
    }
}

// ---------------- scatter edges into CSR order ----------------
__global__ __launch_bounds__(256) void k_scatter(const int* __restrict__ src,
                                                 const int* __restrict__ dst,
                                                 const float* __restrict__ attr,
                                                 int* __restrict__ cursor,
                                                 int* __restrict__ ssorted,
                                                 float* __restrict__ usorted, int E_) {
    int e = blockIdx.x * 256 + threadIdx.x;
    if (e < E_) {
        int d = dst[e];
        int pos = atomicAdd(&cursor[d], 1);
        ssorted[pos] = src[e];
        usorted[pos] = attr[e];
    }
}

// ---------------- dense layer 1: h0 | (h1-h0) interleaved, plus x@root ----------------
__global__ __launch_bounds__(256) void k_dense1(const float* __restrict__ x,
                                                const float* __restrict__ W1,
                                                const float* __restrict__ root1,
                                                float* __restrict__ hd,
                                                float* __restrict__ xr, int n) {
    int node = blockIdx.x * 256 + threadIdx.x;
    if (node >= n) return;
    float xv[32];
    const float4* xp = (const float4*)(x + (size_t)node * 32);
    #pragma unroll
    for (int q = 0; q < 8; q++) {
        float4 t = xp[q];
        xv[4*q+0] = t.x; xv[4*q+1] = t.y; xv[4*q+2] = t.z; xv[4*q+3] = t.w;
    }
    const float* W0 = W1;
    const float* Wb = W1 + 1024;
    for (int j = 0; j < 32; j++) {
        float a0 = 0.f, a1 = 0.f, ar = 0.f;
        #pragma unroll
        for (int i = 0; i < 32; i++) {
            a0 += xv[i] * W0[i * 32 + j];
            a1 += xv[i] * Wb[i * 32 + j];
            ar += xv[i] * root1[i * 32 + j];
        }
        hd[(size_t)node * 64 + j]      = a0;
        hd[(size_t)node * 64 + 32 + j] = a1 - a0;
        xr[(size_t)node * 32 + j]      = ar;
    }
}

// ---------------- aggregation layer 1 (wave per node) ----------------
__global__ __launch_bounds__(256) void k_agg1(const int* __restrict__ rowptr,
                                              const int* __restrict__ ssorted,
                                              const float* __restrict__ usorted,
                                              const float* __restrict__ hd,
                                              const float* __restrict__ xr,
                                              const float* __restrict__ b1,
                                              const int* __restrict__ deg,
                                              float* __restrict__ h, int n) {
    int lane = threadIdx.x & 63;
    int node = blockIdx.x * 4 + (threadIdx.x >> 6);
    if (node >= n) return;
    int start = rowptr[node], end = rowptr[node + 1];
    int col = lane & 31, half = lane >> 5;
    float acc = 0.f;
    for (int j = start; j < end; ++j) {
        int s = ssorted[j];
        float u = usorted[j];
        float v = hd[(size_t)s * 64 + half * 32 + col];
        acc += half ? u * v : v;
    }
    acc += __shfl_xor(acc, 32);
    if (lane < 32) {
        float dg = fmaxf((float)deg[node], 1.0f);
        float val = acc / dg + xr[(size_t)node * 32 + col] + b1[col];
        h[(size_t)node * 32 + col] = fmaxf(val, 0.0f);
    }
}

// ---------------- dense layer 2: g0 | (g1-g0) interleaved (20 cols), plus h@root2 ----------------
__global__ __launch_bounds__(256) void k_dense2(const float* __restrict__ h,
                                                const float* __restrict__ W2,
                                                const float* __restrict__ root2,
                                                float* __restrict__ gg,
                                                float* __restrict__ hr, int n) {
    int node = blockIdx.x * 256 + threadIdx.x;
    if (node >= n) return;
    float hv[32];
    const float4* hp = (const float4*)(h + (size_t)node * 32);
    #pragma unroll
    for (int q = 0; q < 8; q++) {
        float4 t = hp[q];
        hv[4*q+0] = t.x; hv[4*q+1] = t.y; hv[4*q+2] = t.z; hv[4*q+3] = t.w;
    }
    const float* A0 = W2;
    const float* A1 = W2 + 320;
    for (int c = 0; c < 10; c++) {
        float a0 = 0.f, a1 = 0.f, ar = 0.f;
        #pragma unroll
        for (int i = 0; i < 32; i++) {
            a0 += hv[i] * A0[i * 10 + c];
            a1 += hv[i] * A1[i * 10 + c];
            ar += hv[i] * root2[i * 10 + c];
        }
        gg[(size_t)node * 20 + c]      = a0;
        gg[(size_t)node * 20 + 10 + c] = a1 - a0;
        hr[(size_t)node * 10 + c]      = ar;
    }
}

// ---------------- aggregation layer 2 + log_softmax (wave per node) ----------------
__global__ __launch_bounds__(256) void k_agg2(const int* __restrict__ rowptr,
                                              const int* __restrict__ ssorted,
                                              const float* __restrict__ usorted,
                                              const float* __restrict__ gg,
                                              const float* __restrict__ hr,
                                              const float* __restrict__ b2,
                                              const int* __restrict__ deg,
                                              float* __restrict__ out, int n) {
    int lane = threadIdx.x & 63;
    int node = blockIdx.x * 4 + (threadIdx.x >> 6);
    if (node >= n) return;
    int start = rowptr[node], end = rowptr[node + 1];
    int sub = lane / 20;            // 0..2 (lane>=60 inactive)
    int r = lane - sub * 20;        // 0..19
    bool active = lane < 60;
    float acc = 0.f;
    for (int jb = start; jb < end; jb += 3) {
        int idx = jb + sub;
        if (active && idx < end) {
            int s = ssorted[idx];
            float u = usorted[idx];
            float v = gg[(size_t)s * 20 + r];
            acc += (r < 10) ? v : u * v;
        }
    }
    // combine u-part into base part within each 20-lane group
    float a10 = __shfl_down(acc, 10);
    if (r < 10) acc += a10;
    // reduce the 3 sub-groups
    float a20 = __shfl_down(acc, 20);
    float a40 = __shfl_down(acc, 40);
    if (lane < 10) acc += a20 + a40;

    float logit = 0.f;
    if (lane < 10) {
        float dg = fmaxf((float)deg[node], 1.0f);
        logit = acc / dg + hr[(size_t)node * 10 + lane] + b2[lane];
    }
    float m = (lane < 10) ? logit : -INFINITY;
    #pragma unroll
    for (int o = 8; o; o >>= 1) m = fmaxf(m, __shfl_xor(m, o, 16));
    float ex = (lane < 10) ? expf(logit - m) : 0.f;
    #pragma unroll
    for (int o = 8; o; o >>= 1) ex += __shfl_xor(ex, o, 16);
    if (lane < 10) out[(size_t)node * 10 + lane] = logit - m - logf(ex);
}

extern "C" void kernel_launch(void* const* d_in, const int* in_sizes, int n_in,
                              void* d_out, int out_size, void* d_ws, size_t ws_size,
                              hipStream_t stream) {
    const float* x     = (const float*)d_in[0];
    const int*   ei    = (const int*)d_in[1];
    const float* attr  = (const float*)d_in[2];
    const float* W1    = (const float*)d_in[3];
    const float* root1 = (const float*)d_in[4];
    const float* b1    = (const float*)d_in[5];
    const float* W2    = (const float*)d_in[6];
    const float* root2 = (const float*)d_in[7];
    const float* b2    = (const float*)d_in[8];
    float* out = (float*)d_out;

    int N_ = in_sizes[0] / 32;
    int E_ = in_sizes[1] / 2;
    const int* src = ei;
    const int* dst = ei + E_;

    char* ws = (char*)d_ws;
    size_t off = 0;
    auto alloc = [&](size_t bytes) -> void* {
        void* p = ws + off;
        off += (bytes + 255) & ~(size_t)255;
        return p;
    };
    int*   deg     = (int*)  alloc((size_t)N_ * 4);
    int*   rowptr  = (int*)  alloc((size_t)(N_ + 1) * 4);
    int*   cursor  = (int*)  alloc((size_t)N_ * 4);
    int*   ssorted = (int*)  alloc((size_t)E_ * 4);
    float* usorted = (float*)alloc((size_t)E_ * 4);
    float* hd      = (float*)alloc((size_t)N_ * 64 * 4);
    float* xr      = (float*)alloc((size_t)N_ * 32 * 4);
    float* h       = (float*)alloc((size_t)N_ * 32 * 4);
    float* gg      = (float*)alloc((size_t)N_ * 20 * 4);
    float* hr      = (float*)alloc((size_t)N_ * 10 * 4);

    hipMemsetAsync(deg, 0, (size_t)N_ * 4, stream);

    k_hist   <<<(E_ + 255) / 256, 256, 0, stream>>>(dst, deg, E_);
    k_scan   <<<1, 1024, 0, stream>>>(deg, rowptr, cursor, N_);
    k_scatter<<<(E_ + 255) / 256, 256, 0, stream>>>(src, dst, attr, cursor, ssorted, usorted, E_);
    k_dense1 <<<(N_ + 255) / 256, 256, 0, stream>>>(x, W1, root1, hd, xr, N_);
    k_agg1   <<<(N_ + 3) / 4, 256, 0, stream>>>(rowptr, ssorted, usorted, hd, xr, b1, deg, h, N_);
    k_dense2 <<<(N_ + 255) / 256, 256, 0, stream>>>(h, W2, root2, gg, hr, N_);
    k_agg2   <<<(N_ + 3) / 4, 256, 0, stream>>>(rowptr, ssorted, usorted, gg, hr, b2, deg, out, N_);
}

// Round 2
// 357.069 us; speedup vs baseline: 1.4090x; 1.4090x over previous
//
#include <hip/hip_runtime.h>
#include <math.h>

// ---------------- histogram of dst degrees ----------------
__global__ __launch_bounds__(256) void k_hist(const int* __restrict__ dst,
                                              int* __restrict__ deg, int E_) {
    int e = blockIdx.x * 256 + threadIdx.x;
    if (e < E_) atomicAdd(&deg[dst[e]], 1);
}

// ---------------- scan stage 1: per-block (256) local exclusive scan ----------------
__global__ __launch_bounds__(256) void k_scan1(const int* __restrict__ deg,
                                               int* __restrict__ lexcl,
                                               int* __restrict__ partial, int n) {
    __shared__ int wsum[4];
    int tid = threadIdx.x, lane = tid & 63, w = tid >> 6;
    int i = blockIdx.x * 256 + tid;
    int v = (i < n) ? deg[i] : 0;
    int incl = v;
    #pragma unroll
    for (int o = 1; o < 64; o <<= 1) {
        int t = __shfl_up(incl, o);
        if (lane >= o) incl += t;
    }
    if (lane == 63) wsum[w] = incl;
    __syncthreads();
    int woff = 0;
    for (int k = 0; k < w; k++) woff += wsum[k];
    int excl = woff + incl - v;
    if (i < n) lexcl[i] = excl;
    if (tid == 255) partial[blockIdx.x] = woff + incl;
}

// ---------------- scan stage 2: single block scans block partials ----------------
__global__ __launch_bounds__(1024) void k_scan2(const int* __restrict__ partial,
                                                int* __restrict__ blockbase, int nb) {
    __shared__ int wsum[16];
    int tid = threadIdx.x, lane = tid & 63, w = tid >> 6;
    int v = (tid < nb) ? partial[tid] : 0;
    int incl = v;
    #pragma unroll
    for (int o = 1; o < 64; o <<= 1) {
        int t = __shfl_up(incl, o);
        if (lane >= o) incl += t;
    }
    if (lane == 63) wsum[w] = incl;
    __syncthreads();
    int woff = 0;
    for (int k = 0; k < w; k++) woff += wsum[k];
    if (tid < nb) blockbase[tid] = woff + incl - v;
}

// ---------------- scan stage 3: apply block base, build rowptr & cursor ----------------
__global__ __launch_bounds__(256) void k_scan3(const int* __restrict__ deg,
                                               int* __restrict__ cursor,   // holds lexcl on entry
                                               const int* __restrict__ blockbase,
                                               int* __restrict__ rowptr, int n) {
    int i = blockIdx.x * 256 + threadIdx.x;
    if (i >= n) return;
    int e = cursor[i] + blockbase[blockIdx.x];
    cursor[i] = e;
    rowptr[i + 1] = e + deg[i];
    if (i == 0) rowptr[0] = 0;
}

// ---------------- scatter edges into CSR order: (src, u) packed int2 ----------------
__global__ __launch_bounds__(256) void k_scatter(const int* __restrict__ src,
                                                 const int* __restrict__ dst,
                                                 const float* __restrict__ attr,
                                                 int* __restrict__ cursor,
                                                 int2* __restrict__ su, int E_) {
    int e = blockIdx.x * 256 + threadIdx.x;
    if (e < E_) {
        int d = dst[e];
        int pos = atomicAdd(&cursor[d], 1);
        su[pos] = make_int2(src[e], __float_as_int(attr[e]));
    }
}

// ---------------- dense layer 1: hd[n][64] = [h0(32) | h1-h0(32)], xr = x@root1 ----
// 16 threads per node; thread q writes hd cols 4q..4q+3 and xr cols 2q..2q+1.
__global__ __launch_bounds__(256) void k_dense1(const float* __restrict__ x,
                                                const float* __restrict__ W1,
                                                const float* __restrict__ root1,
                                                float* __restrict__ hd,
                                                float* __restrict__ xr, int n) {
    int t = blockIdx.x * 256 + threadIdx.x;
    int node = t >> 4;
    int q = t & 15;
    if (node >= n) return;
    float xv[32];
    const float4* xp = (const float4*)(x + (size_t)node * 32);
    #pragma unroll
    for (int k = 0; k < 8; k++) {
        float4 tt = xp[k];
        xv[4*k+0] = tt.x; xv[4*k+1] = tt.y; xv[4*k+2] = tt.z; xv[4*k+3] = tt.w;
    }
    const float* W0 = W1;
    const float* Wb = W1 + 1024;
    int c0 = q * 4;          // 0..60
    int cc = c0 & 31;        // column within the 32
    float4 a0 = {0,0,0,0}, a1 = {0,0,0,0};
    float r0 = 0.f, r1 = 0.f;
    int rc = q * 2;
    #pragma unroll
    for (int i = 0; i < 32; i++) {
        float xi = xv[i];
        float4 w0 = *(const float4*)(W0 + i * 32 + cc);
        float4 w1 = *(const float4*)(Wb + i * 32 + cc);
        a0.x += xi * w0.x; a0.y += xi * w0.y; a0.z += xi * w0.z; a0.w += xi * w0.w;
        a1.x += xi * w1.x; a1.y += xi * w1.y; a1.z += xi * w1.z; a1.w += xi * w1.w;
        float2 rr = *(const float2*)(root1 + i * 32 + rc);
        r0 += xi * rr.x; r1 += xi * rr.y;
    }
    float4 outv;
    if (c0 < 32) outv = a0;
    else outv = make_float4(a1.x - a0.x, a1.y - a0.y, a1.z - a0.z, a1.w - a0.w);
    *(float4*)(hd + (size_t)node * 64 + c0) = outv;
    *(float2*)(xr + (size_t)node * 32 + rc) = make_float2(r0, r1);
}

// ---------------- aggregation layer 1 (wave per node, 4 edge-slots x float4) ------
__global__ __launch_bounds__(256) void k_agg1(const int* __restrict__ rowptr,
                                              const int2* __restrict__ su,
                                              const float* __restrict__ hd,
                                              const float* __restrict__ xr,
                                              const float* __restrict__ b1,
                                              float* __restrict__ h, int n) {
    int lane = threadIdx.x & 63;
    int node = blockIdx.x * 4 + (threadIdx.x >> 6);
    if (node >= n) return;
    int g = lane >> 4;            // edge slot 0..3
    int l = lane & 15;
    int half = l >> 3;            // 0: h0 part, 1: delta part
    int colb = (l & 7) * 4;       // col base 0..28
    int hoff = half * 32 + colb;
    int start = rowptr[node], end = rowptr[node + 1];
    float4 acc = {0,0,0,0};
    for (int j = start; j < end; j += 8) {
        int i0 = j + g, i1 = j + 4 + g;
        bool v0a = i0 < end, v1a = i1 < end;
        int2 e0 = v0a ? su[i0] : make_int2(0, 0);
        int2 e1 = v1a ? su[i1] : make_int2(0, 0);
        float4 v0 = *(const float4*)(hd + (size_t)e0.x * 64 + hoff);
        float4 v1 = *(const float4*)(hd + (size_t)e1.x * 64 + hoff);
        float w0 = v0a ? (half ? __int_as_float(e0.y) : 1.f) : 0.f;
        float w1 = v1a ? (half ? __int_as_float(e1.y) : 1.f) : 0.f;
        acc.x += w0 * v0.x + w1 * v1.x;
        acc.y += w0 * v0.y + w1 * v1.y;
        acc.z += w0 * v0.z + w1 * v1.z;
        acc.w += w0 * v0.w + w1 * v1.w;
    }
    // reduce the 4 edge slots (lane bits 4,5) then the two halves (bit 3)
    #pragma unroll
    for (int o = 16; o <= 32; o <<= 1) {
        acc.x += __shfl_xor(acc.x, o);
        acc.y += __shfl_xor(acc.y, o);
        acc.z += __shfl_xor(acc.z, o);
        acc.w += __shfl_xor(acc.w, o);
    }
    acc.x += __shfl_xor(acc.x, 8);
    acc.y += __shfl_xor(acc.y, 8);
    acc.z += __shfl_xor(acc.z, 8);
    acc.w += __shfl_xor(acc.w, 8);
    if (lane < 8) {
        float dg = fmaxf((float)(end - start), 1.0f);
        float inv = 1.0f / dg;
        float4 xrv = *(const float4*)(xr + (size_t)node * 32 + lane * 4);
        float4 bv  = *(const float4*)(b1 + lane * 4);
        float4 r;
        r.x = fmaxf(acc.x * inv + xrv.x + bv.x, 0.f);
        r.y = fmaxf(acc.y * inv + xrv.y + bv.y, 0.f);
        r.z = fmaxf(acc.z * inv + xrv.z + bv.z, 0.f);
        r.w = fmaxf(acc.w * inv + xrv.w + bv.w, 0.f);
        *(float4*)(h + (size_t)node * 32 + lane * 4) = r;
    }
}

// ---------------- dense layer 2: gg[n][20] = [g0(10) | g1-g0(10)], hr = h@root2 ----
// 10 threads per node; thread c computes col c of all three products.
__global__ __launch_bounds__(256) void k_dense2(const float* __restrict__ h,
                                                const float* __restrict__ W2,
                                                const float* __restrict__ root2,
                                                float* __restrict__ gg,
                                                float* __restrict__ hr, int n) {
    int t = blockIdx.x * 256 + threadIdx.x;
    int node = t / 10;
    int c = t - node * 10;
    if (node >= n) return;
    float hv[32];
    const float4* hp = (const float4*)(h + (size_t)node * 32);
    #pragma unroll
    for (int k = 0; k < 8; k++) {
        float4 tt = hp[k];
        hv[4*k+0] = tt.x; hv[4*k+1] = tt.y; hv[4*k+2] = tt.z; hv[4*k+3] = tt.w;
    }
    const float* A0 = W2;
    const float* A1 = W2 + 320;
    float a0 = 0.f, a1 = 0.f, ar = 0.f;
    #pragma unroll
    for (int i = 0; i < 32; i++) {
        float hi = hv[i];
        a0 += hi * A0[i * 10 + c];
        a1 += hi * A1[i * 10 + c];
        ar += hi * root2[i * 10 + c];
    }
    gg[(size_t)node * 20 + c]      = a0;
    gg[(size_t)node * 20 + 10 + c] = a1 - a0;
    hr[(size_t)node * 10 + c]      = ar;
}

// ---------------- aggregation layer 2 + log_softmax (wave per node, 6 slots x float2) ----
__global__ __launch_bounds__(256) void k_agg2(const int* __restrict__ rowptr,
                                              const int2* __restrict__ su,
                                              const float* __restrict__ gg,
                                              const float* __restrict__ hr,
                                              const float* __restrict__ b2,
                                              float* __restrict__ out, int n) {
    int lane = threadIdx.x & 63;
    int node = blockIdx.x * 4 + (threadIdx.x >> 6);
    if (node >= n) return;
    int g = lane / 10;               // 0..6 (6 is inactive)
    int l = lane - g * 10;           // 0..9
    bool lact = lane < 60;
    int half = (l >= 5) ? 1 : 0;
    int colb = (l - half * 5) * 2;   // 0,2,4,6,8
    int hoff = half * 10 + colb;
    int start = rowptr[node], end = rowptr[node + 1];
    float2 acc = {0, 0};
    for (int j = start; j < end; j += 12) {
        int i0 = j + g, i1 = j + 6 + g;
        bool v0a = lact && (i0 < end), v1a = lact && (i1 < end);
        int2 e0 = v0a ? su[i0] : make_int2(0, 0);
        int2 e1 = v1a ? su[i1] : make_int2(0, 0);
        float2 v0 = *(const float2*)(gg + (size_t)e0.x * 20 + hoff);
        float2 v1 = *(const float2*)(gg + (size_t)e1.x * 20 + hoff);
        float w0 = v0a ? (half ? __int_as_float(e0.y) : 1.f) : 0.f;
        float w1 = v1a ? (half ? __int_as_float(e1.y) : 1.f) : 0.f;
        acc.x += w0 * v0.x + w1 * v1.x;
        acc.y += w0 * v0.y + w1 * v1.y;
    }
    // reduce 6 slot-groups (lanes l, l+10, ..., l+50)
    float t30x = __shfl_down(acc.x, 30), t30y = __shfl_down(acc.y, 30);
    acc.x += t30x; acc.y += t30y;                    // lanes 0..29 now hold pairs
    float t10x = __shfl_down(acc.x, 10), t10y = __shfl_down(acc.y, 10);
    float t20x = __shfl_down(acc.x, 20), t20y = __shfl_down(acc.y, 20);
    acc.x += t10x + t20x; acc.y += t10y + t20y;      // lanes 0..9 hold slot totals
    // combine halves: lanes 0..4 += lanes 5..9
    float t5x = __shfl_down(acc.x, 5), t5y = __shfl_down(acc.y, 5);
    acc.x += t5x; acc.y += t5y;                      // lanes 0..4: cols 2l,2l+1

    float lx = -INFINITY, ly = -INFINITY;
    if (l < 5 && g == 0) {
        float dg = fmaxf((float)(end - start), 1.0f);
        float inv = 1.0f / dg;
        float2 hrv = *(const float2*)(hr + (size_t)node * 10 + l * 2);
        lx = acc.x * inv + hrv.x + b2[l * 2];
        ly = acc.y * inv + hrv.y + b2[l * 2 + 1];
    }
    // softmax across lanes 0..4 (2 cols each), within an 8-lane group
    float m = fmaxf(lx, ly);
    #pragma unroll
    for (int o = 4; o; o >>= 1) m = fmaxf(m, __shfl_xor(m, o, 8));
    float ex = 0.f;
    if (l < 5 && g == 0) ex = __expf(lx - m) + __expf(ly - m);
    #pragma unroll
    for (int o = 4; o; o >>= 1) ex += __shfl_xor(ex, o, 8);
    if (l < 5 && g == 0) {
        float lg = m + __logf(ex);
        *(float2*)(out + (size_t)node * 10 + l * 2) = make_float2(lx - lg, ly - lg);
    }
}

extern "C" void kernel_launch(void* const* d_in, const int* in_sizes, int n_in,
                              void* d_out, int out_size, void* d_ws, size_t ws_size,
                              hipStream_t stream) {
    const float* x     = (const float*)d_in[0];
    const int*   ei    = (const int*)d_in[1];
    const float* attr  = (const float*)d_in[2];
    const float* W1    = (const float*)d_in[3];
    const float* root1 = (const float*)d_in[4];
    const float* b1    = (const float*)d_in[5];
    const float* W2    = (const float*)d_in[6];
    const float* root2 = (const float*)d_in[7];
    const float* b2    = (const float*)d_in[8];
    float* out = (float*)d_out;

    int N_ = in_sizes[0] / 32;
    int E_ = in_sizes[1] / 2;
    const int* src = ei;
    const int* dst = ei + E_;

    char* ws = (char*)d_ws;
    size_t off = 0;
    auto alloc = [&](size_t bytes) -> void* {
        void* p = ws + off;
        off += (bytes + 255) & ~(size_t)255;
        return p;
    };
    int nb = (N_ + 255) / 256;
    int*   deg       = (int*)  alloc((size_t)N_ * 4);
    int*   rowptr    = (int*)  alloc((size_t)(N_ + 1) * 4);
    int*   cursor    = (int*)  alloc((size_t)N_ * 4);
    int*   partial   = (int*)  alloc((size_t)nb * 4);
    int*   blockbase = (int*)  alloc((size_t)nb * 4);
    int2*  su        = (int2*) alloc((size_t)E_ * 8);
    float* hd        = (float*)alloc((size_t)N_ * 64 * 4);
    float* xr        = (float*)alloc((size_t)N_ * 32 * 4);
    float* h         = (float*)alloc((size_t)N_ * 32 * 4);
    float* gg        = (float*)alloc((size_t)N_ * 20 * 4);
    float* hr        = (float*)alloc((size_t)N_ * 10 * 4);

    hipMemsetAsync(deg, 0, (size_t)N_ * 4, stream);

    k_hist   <<<(E_ + 255) / 256, 256, 0, stream>>>(dst, deg, E_);
    k_scan1  <<<nb, 256, 0, stream>>>(deg, cursor, partial, N_);
    k_scan2  <<<1, 1024, 0, stream>>>(partial, blockbase, nb);
    k_scan3  <<<nb, 256, 0, stream>>>(deg, cursor, blockbase, rowptr, N_);
    k_scatter<<<(E_ + 255) / 256, 256, 0, stream>>>(src, dst, attr, cursor, su, E_);
    k_dense1 <<<((N_ * 16) + 255) / 256, 256, 0, stream>>>(x, W1, root1, hd, xr, N_);
    k_agg1   <<<(N_ + 3) / 4, 256, 0, stream>>>(rowptr, su, hd, xr, b1, h, N_);
    k_dense2 <<<((N_ * 10) + 255) / 256, 256, 0, stream>>>(h, W2, root2, gg, hr, N_);
    k_agg2   <<<(N_ + 3) / 4, 256, 0, stream>>>(rowptr, su, gg, hr, b2, out, N_);
}